// Round 14
// baseline (429.391 us; speedup 1.0000x reference)
//
#include <hip/hip_runtime.h>
#include <math.h>
#include <stdint.h>

// ---------------------------------------------------------------------------
// GATv2 3-layer network on MI355X.
//   1) CSR build by dst (deg count -> 3-kernel scan -> scatter).
//   2) Weights (6 layer mats + classifier) pre-packed into MFMA B-fragment
//      order as bf16 hi/lo pairs (classifier zero-padded 40 -> 48 cols).
//   3) Per layer: ONE fused MFMA kernel computes xl=h@Wl+bl and xr=h@Wr+br,
//      both emitted fp16, via split-bf16. Hidden state h fp16 end-to-end.
//      Attention: one wave per dst node; group geometry templated:
//        DOUT=256: 4 groups x 16 lanes (4 edges/iter)  [r8/r12 structure]
//        DOUT=128: 8 groups x 8 lanes  (8 edges/iter)  [halves fixed costs]
//      Each lane covers 16 elements via 2x half8 (32B). r8's 3-stage shift
//      pipeline (measured best), packed-fp16 score, defer-max (THR=8),
//      mixed-precision aggregation, fp16 out.
//   4) Classifier via MFMA (fp16 input).
// ---------------------------------------------------------------------------

typedef __attribute__((ext_vector_type(8))) short bf16x8;
typedef __attribute__((ext_vector_type(4))) float f32x4;
typedef __attribute__((ext_vector_type(4))) _Float16 half4;
typedef __attribute__((ext_vector_type(8))) _Float16 half8;
typedef __attribute__((ext_vector_type(2))) _Float16 half2v;
typedef unsigned short ushort_t;

__device__ inline ushort_t bf16_rne(float f) {
  unsigned u = __float_as_uint(f);
  unsigned r = (u + 0x7FFFu + ((u >> 16) & 1u)) >> 16;
  return (ushort_t)r;
}
__device__ inline float bf16_to_f(ushort_t h) {
  return __uint_as_float(((unsigned)h) << 16);
}

__device__ inline float fdot2f(half2v a, half2v b, float c) {
#if __has_builtin(__builtin_amdgcn_fdot2)
  return __builtin_amdgcn_fdot2(a, b, c, false);
#else
  return c + (float)a[0] * (float)b[0] + (float)a[1] * (float)b[1];
#endif
}
__device__ inline half2v h2max(half2v a, half2v b) {
#if __has_builtin(__builtin_elementwise_max)
  return __builtin_elementwise_max(a, b);
#else
  half2v r;
  r[0] = a[0] > b[0] ? a[0] : b[0];
  r[1] = a[1] > b[1] ? a[1] : b[1];
  return r;
#endif
}

__global__ void zero_int_kernel(int* __restrict__ p, int n) {
  int i = blockIdx.x * blockDim.x + threadIdx.x;
  if (i < n) p[i] = 0;
}

__global__ void deg_count_kernel(const int* __restrict__ dst, int E, int n,
                                 int* __restrict__ deg) {
  int i = blockIdx.x * blockDim.x + threadIdx.x;
  int tot = E + n;
  if (i < tot) {
    int d = (i < E) ? dst[i] : (i - E);
    atomicAdd(&deg[d], 1);
  }
}

// 3-phase exclusive scan over deg[n], chunk=1024. nchunks must be <= 64.
__global__ __launch_bounds__(256) void block_sum_kernel(
    const int* __restrict__ deg, int n, int* __restrict__ partial) {
  __shared__ int sm[256];
  int base = blockIdx.x * 1024;
  int t = threadIdx.x;
  int sum = 0;
#pragma unroll
  for (int k = 0; k < 4; ++k) {
    int i = base + k * 256 + t;
    sum += (i < n) ? deg[i] : 0;
  }
  sm[t] = sum;
  __syncthreads();
  for (int off = 128; off > 0; off >>= 1) {
    if (t < off) sm[t] += sm[t + off];
    __syncthreads();
  }
  if (t == 0) partial[blockIdx.x] = sm[0];
}

__global__ void scan_partial_kernel(int* __restrict__ partial, int nchunks) {
  int lane = threadIdx.x;  // 64 threads
  int v = (lane < nchunks) ? partial[lane] : 0;
#pragma unroll
  for (int off = 1; off < 64; off <<= 1) {
    int u = __shfl_up(v, off, 64);
    if (lane >= off) v += u;
  }
  int ex = __shfl_up(v, 1, 64);
  if (lane == 0) ex = 0;
  if (lane < nchunks) partial[lane] = ex;
}

__global__ __launch_bounds__(1024) void block_scan_kernel(
    const int* __restrict__ deg, const int* __restrict__ partial,
    int* __restrict__ row_ptr, int* __restrict__ cursor, int n) {
  __shared__ int sm[1024];
  int i = blockIdx.x * 1024 + threadIdx.x;
  int v = (i < n) ? deg[i] : 0;
  sm[threadIdx.x] = v;
  __syncthreads();
  for (int off = 1; off < 1024; off <<= 1) {
    int t = (threadIdx.x >= off) ? sm[threadIdx.x - off] : 0;
    __syncthreads();
    sm[threadIdx.x] += t;
    __syncthreads();
  }
  int excl = partial[blockIdx.x] + sm[threadIdx.x] - v;
  if (i < n) {
    row_ptr[i] = excl;
    cursor[i] = excl;
  }
  if (i == n - 1) row_ptr[n] = excl + v;
}

__global__ void scatter_kernel(const int* __restrict__ src,
                               const int* __restrict__ dst, int E, int n,
                               int* __restrict__ cursor,
                               int* __restrict__ col_src) {
  int i = blockIdx.x * blockDim.x + threadIdx.x;
  int tot = E + n;
  if (i < tot) {
    int s = (i < E) ? src[i] : (i - E);
    int d = (i < E) ? dst[i] : (i - E);
    int slot = atomicAdd(&cursor[d], 1);
    col_src[slot] = s;
  }
}

// --------------------------- weight packing --------------------------------
// Fragment order for mfma_f32_16x16x32_bf16 B operand:
//   idx = ((ks*ntiles + t)*64 + lane)*8 + i -> W[ks*32+8*(lane>>4)+i][16t+(lane&15)]
// Zero-pads columns c >= N (classifier: 40 cols padded to 3 tiles = 48).
struct PackArgs {
  const float* w[7];
  ushort_t* hi[7];
  ushort_t* lo[7];
  int ntiles[7];
  int kslices[7];
  int N[7];
};

__global__ __launch_bounds__(256) void pack_w_kernel(PackArgs a) {
  int m = blockIdx.y;
  int ntiles = a.ntiles[m];
  int N = a.N[m];
  int tot = a.kslices[m] * ntiles * 512;
  int idx = blockIdx.x * 256 + threadIdx.x;
  if (idx >= tot) return;
  int i = idx & 7;
  int lane = (idx >> 3) & 63;
  int t = (idx >> 9) % ntiles;
  int ks = idx / (512 * ntiles);
  int k = ks * 32 + (lane >> 4) * 8 + i;
  int c = t * 16 + (lane & 15);
  float f = (c < N) ? a.w[m][k * N + c] : 0.f;
  ushort_t h = bf16_rne(f);
  a.hi[m][idx] = h;
  a.lo[m][idx] = bf16_rne(f - bf16_to_f(h));
}

// ----------------------- fused dual MFMA GEMM ------------------------------
// Yl (fp16) = X@Wl+Bl, Yr (fp16) = X@Wr+Br.  X: [M][128] fp32 OR fp16.
// Block: 256 thr = 4 waves; wave handles 16 rows x 128 cols (8 16x16 tiles).
// grid.y selects a 128-col panel (for N=256).
template <typename TIN>
__global__ __launch_bounds__(256) void gemm_dual_mfma(
    const TIN* __restrict__ X, const ushort_t* __restrict__ wlhi,
    const ushort_t* __restrict__ wllo, const ushort_t* __restrict__ wrhi,
    const ushort_t* __restrict__ wrlo, const float* __restrict__ Bl,
    const float* __restrict__ Br, _Float16* __restrict__ Yl,
    _Float16* __restrict__ Yr, int M, int N, int ntot) {
  int lane = threadIdx.x & 63;
  int wv = threadIdx.x >> 6;
  int kg = lane >> 4;  // 0..3
  int li = lane & 15;
  int rbase = blockIdx.x * 64 + wv * 16;
  int colofs = blockIdx.y * 128;
  int tbase = colofs >> 4;
  int arow = rbase + li;
  int ar = (arow < M) ? arow : (M - 1);
  const TIN* xp = X + (size_t)ar * 128 + kg * 8;

  f32x4 accl[8], accr[8];
#pragma unroll
  for (int t = 0; t < 8; ++t) {
    accl[t] = (f32x4){0.f, 0.f, 0.f, 0.f};
    accr[t] = (f32x4){0.f, 0.f, 0.f, 0.f};
  }

#pragma unroll
  for (int ks = 0; ks < 4; ++ks) {
    float av[8];
    if constexpr (sizeof(TIN) == 4) {
      float4 a0 = *reinterpret_cast<const float4*>(xp + ks * 32);
      float4 a1 = *reinterpret_cast<const float4*>(xp + ks * 32 + 4);
      av[0] = a0.x; av[1] = a0.y; av[2] = a0.z; av[3] = a0.w;
      av[4] = a1.x; av[5] = a1.y; av[6] = a1.z; av[7] = a1.w;
    } else {
      half8 h8 = *reinterpret_cast<const half8*>(xp + ks * 32);
#pragma unroll
      for (int i = 0; i < 8; ++i) av[i] = (float)h8[i];
    }
    bf16x8 ah, al;
#pragma unroll
    for (int i = 0; i < 8; ++i) {
      ushort_t h = bf16_rne(av[i]);
      ah[i] = (short)h;
      al[i] = (short)bf16_rne(av[i] - bf16_to_f(h));
    }
    size_t fb = ((size_t)ks * ntot + tbase) * 512 + (size_t)lane * 8;
#pragma unroll
    for (int t = 0; t < 8; ++t) {
      size_t o = fb + (size_t)t * 512;
      bf16x8 blh = *reinterpret_cast<const bf16x8*>(wlhi + o);
      bf16x8 bll = *reinterpret_cast<const bf16x8*>(wllo + o);
      bf16x8 brh = *reinterpret_cast<const bf16x8*>(wrhi + o);
      bf16x8 brl = *reinterpret_cast<const bf16x8*>(wrlo + o);
      accl[t] = __builtin_amdgcn_mfma_f32_16x16x32_bf16(ah, blh, accl[t], 0, 0, 0);
      accl[t] = __builtin_amdgcn_mfma_f32_16x16x32_bf16(ah, bll, accl[t], 0, 0, 0);
      accl[t] = __builtin_amdgcn_mfma_f32_16x16x32_bf16(al, blh, accl[t], 0, 0, 0);
      accr[t] = __builtin_amdgcn_mfma_f32_16x16x32_bf16(ah, brh, accr[t], 0, 0, 0);
      accr[t] = __builtin_amdgcn_mfma_f32_16x16x32_bf16(ah, brl, accr[t], 0, 0, 0);
      accr[t] = __builtin_amdgcn_mfma_f32_16x16x32_bf16(al, brh, accr[t], 0, 0, 0);
    }
  }
  // D layout: row = 4*(lane>>4)+reg, col = 16t + (lane&15)
  int srow = rbase + kg * 4;
#pragma unroll
  for (int t = 0; t < 8; ++t) {
    int col = colofs + t * 16 + li;
    float bl = Bl[col];
    float br = Br[col];
#pragma unroll
    for (int r = 0; r < 4; ++r) {
      int rr = srow + r;
      if (rr < M) {
        Yl[(size_t)rr * N + col] = (_Float16)(accl[t][r] + bl);
        Yr[(size_t)rr * N + col] = (_Float16)(accr[t][r] + br);
      }
    }
  }
}

// ----------------------- classifier via MFMA -------------------------------
// out[M][40] = H[M][256] @ WC[256][40] + BC.  H fp16. WC packed to 3 tiles.
__global__ __launch_bounds__(256) void classifier_mfma(
    const _Float16* __restrict__ H, const ushort_t* __restrict__ wchi,
    const ushort_t* __restrict__ wclo, const float* __restrict__ BC,
    float* __restrict__ out, int M) {
  int lane = threadIdx.x & 63;
  int wv = threadIdx.x >> 6;
  int kg = lane >> 4;
  int li = lane & 15;
  int rbase = blockIdx.x * 64 + wv * 16;
  int arow = rbase + li;
  int ar = (arow < M) ? arow : (M - 1);
  const _Float16* xp = H + (size_t)ar * 256 + kg * 8;

  f32x4 acc[3];
#pragma unroll
  for (int t = 0; t < 3; ++t) acc[t] = (f32x4){0.f, 0.f, 0.f, 0.f};

#pragma unroll
  for (int ks = 0; ks < 8; ++ks) {
    half8 h8 = *reinterpret_cast<const half8*>(xp + ks * 32);
    bf16x8 ah, al;
#pragma unroll
    for (int i = 0; i < 8; ++i) {
      float f = (float)h8[i];
      ushort_t h = bf16_rne(f);
      ah[i] = (short)h;
      al[i] = (short)bf16_rne(f - bf16_to_f(h));
    }
    size_t fb = ((size_t)ks * 3) * 512 + (size_t)lane * 8;
#pragma unroll
    for (int t = 0; t < 3; ++t) {
      size_t o = fb + (size_t)t * 512;
      bf16x8 bh = *reinterpret_cast<const bf16x8*>(wchi + o);
      bf16x8 bl = *reinterpret_cast<const bf16x8*>(wclo + o);
      acc[t] = __builtin_amdgcn_mfma_f32_16x16x32_bf16(ah, bh, acc[t], 0, 0, 0);
      acc[t] = __builtin_amdgcn_mfma_f32_16x16x32_bf16(ah, bl, acc[t], 0, 0, 0);
      acc[t] = __builtin_amdgcn_mfma_f32_16x16x32_bf16(al, bh, acc[t], 0, 0, 0);
    }
  }
  int srow = rbase + kg * 4;
#pragma unroll
  for (int t = 0; t < 3; ++t) {
    int col = t * 16 + li;
    if (col < 40) {
      float b = BC[col];
#pragma unroll
      for (int r = 0; r < 4; ++r) {
        int rr = srow + r;
        if (rr < M) out[(size_t)rr * 40 + col] = acc[t][r] + b;
      }
    }
  }
}

// --------------------------- attention -------------------------------------
// One wave per dst node. Group geometry: LPG lanes/group, GRPS=64/LPG edge
// streams per wave (DOUT=256: 16x4; DOUT=128: 8x8 -> 8 edges/iter, halved
// fixed costs). Each lane covers 16 elements via 2x half8 (32B). r8's
// 3-stage shift pipeline, packed-fp16 score, defer-max, mix-fma aggregation.
#define NEG_BIG (-1e30f)
template <int DOUT, bool RELU>
__global__ __launch_bounds__(256) void attn_kernel(
    const _Float16* __restrict__ xl, const _Float16* __restrict__ xr,
    const float* __restrict__ att, const float* __restrict__ bias,
    const int* __restrict__ row_ptr, const int* __restrict__ col_src,
    _Float16* __restrict__ out, int M) {
  constexpr int LPG = (DOUT == 128) ? 8 : 16;  // lanes per group
  constexpr int GRPS = 64 / LPG;               // edges per iteration
  constexpr int NQ8 = 2;                       // half8 loads per lane
  constexpr int NE = 16;                       // fp32 acc elems per lane
  int wid = (int)((blockIdx.x * blockDim.x + threadIdx.x) >> 6);
  int lane = threadIdx.x & 63;
  int grp = lane / LPG;
  int sl = lane % LPG;
  if (wid >= M) return;

  // per-lane columns: chunk q covers cols q*(LPG*8) + sl*8 + [0,8)
  half2v xr2[NE / 2], att2[NE / 2];
  {
    const half8* xrp =
        reinterpret_cast<const half8*>(xr) + (size_t)wid * (DOUT / 8) + sl;
#pragma unroll
    for (int q = 0; q < NQ8; ++q) {
      half8 r8 = xrp[q * LPG];
#pragma unroll
      for (int t = 0; t < 4; ++t) {
        half2v v;
        v[0] = r8[2 * t];
        v[1] = r8[2 * t + 1];
        xr2[q * 4 + t] = v;
      }
    }
#pragma unroll
    for (int q = 0; q < NQ8; ++q) {
#pragma unroll
      for (int t = 0; t < 4; ++t) {
        int c = q * (LPG * 8) + sl * 8 + t * 2;
        half2v a2;
        a2[0] = (_Float16)att[c];
        a2[1] = (_Float16)att[c + 1];
        att2[q * 4 + t] = a2;
      }
    }
  }
  half2v v02;
  v02[0] = (_Float16)0.2f;
  v02[1] = (_Float16)0.2f;

  float acc[NE];
#pragma unroll
  for (int i = 0; i < NE; ++i) acc[i] = 0.f;
  float m = NEG_BIG, s = 0.f;
  int e0 = row_ptr[wid], e1 = row_ptr[wid + 1];
  int j = e0 + grp;  // this group's edge stream: j, j+GRPS, j+2*GRPS, ...

  const half8* base = reinterpret_cast<const half8*>(xl);
  half8 xv[NQ8], xn[NQ8], x2[NQ8];
  half8 hz;
#pragma unroll
  for (int i = 0; i < 8; ++i) hz[i] = (_Float16)0.f;
#pragma unroll
  for (int q = 0; q < NQ8; ++q) {
    xv[q] = hz;
    xn[q] = hz;
    x2[q] = hz;
  }
  if (j < e1) {
    const half8* rp = base + (size_t)col_src[j] * (DOUT / 8) + sl;
#pragma unroll
    for (int q = 0; q < NQ8; ++q) xv[q] = rp[q * LPG];
  }
  if (j + GRPS < e1) {
    const half8* rp = base + (size_t)col_src[j + GRPS] * (DOUT / 8) + sl;
#pragma unroll
    for (int q = 0; q < NQ8; ++q) xn[q] = rp[q * LPG];
  }
  int i2 = (j + 2 * GRPS < e1) ? col_src[j + 2 * GRPS] : 0;

  while (j < e1) {
    int i3 = (j + 3 * GRPS < e1) ? col_src[j + 3 * GRPS] : 0;  // index prefetch
    if (j + 2 * GRPS < e1) {  // issue gather 2 iterations ahead
      const half8* rp = base + (size_t)i2 * (DOUT / 8) + sl;
#pragma unroll
      for (int q = 0; q < NQ8; ++q) x2[q] = rp[q * LPG];
    }
    // packed fp16 score
    float p = 0.f;
#pragma unroll
    for (int q = 0; q < NQ8; ++q) {
#pragma unroll
      for (int t = 0; t < 4; ++t) {
        half2v xa;
        xa[0] = xv[q][2 * t];
        xa[1] = xv[q][2 * t + 1];
        half2v tt = xa + xr2[q * 4 + t];
        tt = h2max(tt, tt * v02);  // leaky_relu 0.2
        p = fdot2f(tt, att2[q * 4 + t], p);
      }
    }
#pragma unroll
    for (int off = 1; off < LPG; off <<= 1) p += __shfl_xor(p, off, 64);
    // mixed-precision aggregation straight from the fp16 buffer
    if (p > m + 8.0f) {  // rare: move reference max
      float sc = __expf(m - p);
      s = s * sc + 1.f;
#pragma unroll
      for (int q = 0; q < NQ8; ++q)
#pragma unroll
        for (int u = 0; u < 8; ++u)
          acc[q * 8 + u] = fmaf(acc[q * 8 + u], sc, (float)xv[q][u]);
      m = p;
    } else {  // common: no rescale, p - m <= 8 so pe <= e^8
      float pe = __expf(p - m);
      s += pe;
#pragma unroll
      for (int q = 0; q < NQ8; ++q)
#pragma unroll
        for (int u = 0; u < 8; ++u)
          acc[q * 8 + u] = fmaf(pe, (float)xv[q][u], acc[q * 8 + u]);
    }
#pragma unroll
    for (int q = 0; q < NQ8; ++q) {
      xv[q] = xn[q];
      xn[q] = x2[q];
    }
    i2 = i3;
    j += GRPS;
  }
  // merge (m, s) across the GRPS groups (m is each group's reference point)
  float mg = m;
  float mm = m, ss = s;
#pragma unroll
  for (int off = LPG; off < 64; off <<= 1) {
    float mo = __shfl_xor(mm, off, 64);
    float so = __shfl_xor(ss, off, 64);
    float nm = fmaxf(mm, mo);
    ss = ss * __expf(mm - nm) + so * __expf(mo - nm);
    mm = nm;
  }
  float scale = __expf(mg - mm) / ss;  // ss > 0 (deg >= 1 via self-loop)
#pragma unroll
  for (int i = 0; i < NE; ++i) {
    float v = acc[i] * scale;
#pragma unroll
    for (int off = LPG; off < 64; off <<= 1) v += __shfl_xor(v, off, 64);
    acc[i] = v;
  }
  // write: exactly 4 writer groups in both geometries; group g writes
  // chunk q = g>>1, half hf = g&1: cols q*(LPG*8) + sl*8 + hf*4 + [0,4).
  if (grp < 4) {
    int q = grp >> 1, hf = grp & 1;
    int c = q * (LPG * 8) + sl * 8 + hf * 4;
    float4 b4 = *reinterpret_cast<const float4*>(bias + c);
    float o0 = acc[q * 8 + hf * 4 + 0] + b4.x;
    float o1 = acc[q * 8 + hf * 4 + 1] + b4.y;
    float o2 = acc[q * 8 + hf * 4 + 2] + b4.z;
    float o3 = acc[q * 8 + hf * 4 + 3] + b4.w;
    if (RELU) {
      o0 = fmaxf(o0, 0.f); o1 = fmaxf(o1, 0.f);
      o2 = fmaxf(o2, 0.f); o3 = fmaxf(o3, 0.f);
    }
    half4 oh;
    oh[0] = (_Float16)o0; oh[1] = (_Float16)o1;
    oh[2] = (_Float16)o2; oh[3] = (_Float16)o3;
    *reinterpret_cast<half4*>(out + (size_t)wid * DOUT + c) = oh;
  }
}

extern "C" void kernel_launch(void* const* d_in, const int* in_sizes, int n_in,
                              void* d_out, int out_size, void* d_ws,
                              size_t ws_size, hipStream_t stream) {
  const float* x = (const float*)d_in[0];
  const int* ei = (const int*)d_in[1];
  const float* w1l = (const float*)d_in[2];
  const float* b1l = (const float*)d_in[3];
  const float* w1r = (const float*)d_in[4];
  const float* b1r = (const float*)d_in[5];
  const float* a1 = (const float*)d_in[6];
  const float* o1 = (const float*)d_in[7];
  const float* w2l = (const float*)d_in[8];
  const float* b2l = (const float*)d_in[9];
  const float* w2r = (const float*)d_in[10];
  const float* b2r = (const float*)d_in[11];
  const float* a2 = (const float*)d_in[12];
  const float* o2 = (const float*)d_in[13];
  const float* w3l = (const float*)d_in[14];
  const float* b3l = (const float*)d_in[15];
  const float* w3r = (const float*)d_in[16];
  const float* b3r = (const float*)d_in[17];
  const float* a3 = (const float*)d_in[18];
  const float* o3 = (const float*)d_in[19];
  const float* wc = (const float*)d_in[20];
  const float* bc = (const float*)d_in[21];
  float* out = (float*)d_out;

  const int n = in_sizes[0] / 128;  // 50000
  const int E = in_sizes[1] / 2;    // 800000
  const int tot = E + n;
  const int nchunks = (n + 1023) / 1024;  // <= 64 required

  // workspace layout
  char* p = (char*)d_ws;
  int* row_ptr = (int*)p; p += (size_t)(n + 1) * 4;
  int* deg = (int*)p;     p += (size_t)n * 4;
  int* cursor = (int*)p;  p += (size_t)n * 4;
  int* partial = (int*)p; p += (size_t)64 * 4;
  int* col_src = (int*)p; p += (size_t)tot * 4;
  p = (char*)(((uintptr_t)p + 255) & ~(uintptr_t)255);
  // packed weights: layers 1,2: 16384 elems; layer 3: 32768; wc: 12288
  const size_t SZ12 = 16384, SZ3 = 32768, SZC = 12288;
  ushort_t* pk[14];
  for (int i = 0; i < 8; ++i) { pk[i] = (ushort_t*)p; p += SZ12 * 2; }
  for (int i = 8; i < 12; ++i) { pk[i] = (ushort_t*)p; p += SZ3 * 2; }
  for (int i = 12; i < 14; ++i) { pk[i] = (ushort_t*)p; p += SZC * 2; }
  p = (char*)(((uintptr_t)p + 255) & ~(uintptr_t)255);
  _Float16* bufA = (_Float16*)p; p += (size_t)n * 256 * 2;  // h (fp16)
  _Float16* bufL = (_Float16*)p; p += (size_t)n * 256 * 2;  // xl (fp16)
  _Float16* bufR = (_Float16*)p;                            // xr (fp16)

  const int TPB = 256;

  // CSR build
  zero_int_kernel<<<(n + TPB - 1) / TPB, TPB, 0, stream>>>(deg, n);
  deg_count_kernel<<<(tot + TPB - 1) / TPB, TPB, 0, stream>>>(ei + E, E, n, deg);
  block_sum_kernel<<<nchunks, 256, 0, stream>>>(deg, n, partial);
  scan_partial_kernel<<<1, 64, 0, stream>>>(partial, nchunks);
  block_scan_kernel<<<nchunks, 1024, 0, stream>>>(deg, partial, row_ptr, cursor, n);
  scatter_kernel<<<(tot + TPB - 1) / TPB, TPB, 0, stream>>>(ei, ei + E, E, n,
                                                            cursor, col_src);

  // pack 6 weight matrices + classifier into MFMA B-fragment hi/lo arrays
  PackArgs pa;
  pa.w[0] = w1l; pa.w[1] = w1r; pa.w[2] = w2l; pa.w[3] = w2r;
  pa.w[4] = w3l; pa.w[5] = w3r; pa.w[6] = wc;
  pa.hi[0] = pk[0]; pa.lo[0] = pk[1];
  pa.hi[1] = pk[2]; pa.lo[1] = pk[3];
  pa.hi[2] = pk[4]; pa.lo[2] = pk[5];
  pa.hi[3] = pk[6]; pa.lo[3] = pk[7];
  pa.hi[4] = pk[8]; pa.lo[4] = pk[9];
  pa.hi[5] = pk[10]; pa.lo[5] = pk[11];
  pa.hi[6] = pk[12]; pa.lo[6] = pk[13];
  pa.ntiles[0] = pa.ntiles[1] = pa.ntiles[2] = pa.ntiles[3] = 8;
  pa.ntiles[4] = pa.ntiles[5] = 16;
  pa.ntiles[6] = 3;
  pa.kslices[0] = pa.kslices[1] = pa.kslices[2] = pa.kslices[3] = 4;
  pa.kslices[4] = pa.kslices[5] = 4;
  pa.kslices[6] = 8;
  pa.N[0] = pa.N[1] = pa.N[2] = pa.N[3] = 128;
  pa.N[4] = pa.N[5] = 256;
  pa.N[6] = 40;
  pack_w_kernel<<<dim3(128, 7), 256, 0, stream>>>(pa);

  const int gemmGrid = (n + 63) / 64;
  const int waveGrid = (n + 3) / 4;

  // Layer 1 (128 -> 128) + ReLU   (fp32 input x)
  gemm_dual_mfma<float><<<dim3(gemmGrid, 1), TPB, 0, stream>>>(
      x, pk[0], pk[1], pk[2], pk[3], b1l, b1r, bufL, bufR, n, 128, 8);
  attn_kernel<128, true><<<waveGrid, TPB, 0, stream>>>(bufL, bufR, a1, o1,
                                                       row_ptr, col_src, bufA, n);
  // Layer 2 (128 -> 128) + ReLU   (fp16 input h)
  gemm_dual_mfma<_Float16><<<dim3(gemmGrid, 1), TPB, 0, stream>>>(
      bufA, pk[4], pk[5], pk[6], pk[7], b2l, b2r, bufL, bufR, n, 128, 8);
  attn_kernel<128, true><<<waveGrid, TPB, 0, stream>>>(bufL, bufR, a2, o2,
                                                       row_ptr, col_src, bufA, n);
  // Layer 3 (128 -> 256), no ReLU (fp16 input h)
  gemm_dual_mfma<_Float16><<<dim3(gemmGrid, 2), TPB, 0, stream>>>(
      bufA, pk[8], pk[9], pk[10], pk[11], b3l, b3r, bufL, bufR, n, 256, 16);
  attn_kernel<256, false><<<waveGrid, TPB, 0, stream>>>(bufL, bufR, a3, o3,
                                                        row_ptr, col_src, bufA, n);
  // Classifier (256 -> 40) via MFMA (fp16 input h)
  classifier_mfma<<<gemmGrid, TPB, 0, stream>>>(bufA, pk[12], pk[13], bc, out, n);
}

// Round 15
// 407.938 us; speedup vs baseline: 1.0526x; 1.0526x over previous
//
#include <hip/hip_runtime.h>
#include <math.h>
#include <stdint.h>

// ---------------------------------------------------------------------------
// GATv2 3-layer network on MI355X.  (r13 configuration — measured best.)
//   1) CSR build by dst (deg count -> 3-kernel scan -> scatter).
//   2) Weights (6 layer mats + classifier) pre-packed into MFMA B-fragment
//      order as bf16 hi/lo pairs (classifier zero-padded 40 -> 48 cols).
//   3) Per layer: ONE fused MFMA kernel computes xl=h@Wl+bl and xr=h@Wr+br,
//      both emitted fp16, via split-bf16. Hidden state h fp16 end-to-end.
//      Attention: one wave per dst node, 4x 16-lane edge groups; r8's
//      3-stage SHIFT pipeline (measured best across r9/r10/r11/r14
//      variants), half8 16B gathers, packed-fp16 score, defer-max (THR=8),
//      mixed-precision aggregation, fp16 out.
//   4) Classifier via MFMA (fp16 input).
// ---------------------------------------------------------------------------

typedef __attribute__((ext_vector_type(8))) short bf16x8;
typedef __attribute__((ext_vector_type(4))) float f32x4;
typedef __attribute__((ext_vector_type(4))) _Float16 half4;
typedef __attribute__((ext_vector_type(8))) _Float16 half8;
typedef __attribute__((ext_vector_type(2))) _Float16 half2v;
typedef unsigned short ushort_t;

__device__ inline ushort_t bf16_rne(float f) {
  unsigned u = __float_as_uint(f);
  unsigned r = (u + 0x7FFFu + ((u >> 16) & 1u)) >> 16;
  return (ushort_t)r;
}
__device__ inline float bf16_to_f(ushort_t h) {
  return __uint_as_float(((unsigned)h) << 16);
}

__device__ inline float fdot2f(half2v a, half2v b, float c) {
#if __has_builtin(__builtin_amdgcn_fdot2)
  return __builtin_amdgcn_fdot2(a, b, c, false);
#else
  return c + (float)a[0] * (float)b[0] + (float)a[1] * (float)b[1];
#endif
}
__device__ inline half2v h2max(half2v a, half2v b) {
#if __has_builtin(__builtin_elementwise_max)
  return __builtin_elementwise_max(a, b);
#else
  half2v r;
  r[0] = a[0] > b[0] ? a[0] : b[0];
  r[1] = a[1] > b[1] ? a[1] : b[1];
  return r;
#endif
}

__global__ void zero_int_kernel(int* __restrict__ p, int n) {
  int i = blockIdx.x * blockDim.x + threadIdx.x;
  if (i < n) p[i] = 0;
}

__global__ void deg_count_kernel(const int* __restrict__ dst, int E, int n,
                                 int* __restrict__ deg) {
  int i = blockIdx.x * blockDim.x + threadIdx.x;
  int tot = E + n;
  if (i < tot) {
    int d = (i < E) ? dst[i] : (i - E);
    atomicAdd(&deg[d], 1);
  }
}

// 3-phase exclusive scan over deg[n], chunk=1024. nchunks must be <= 64.
__global__ __launch_bounds__(256) void block_sum_kernel(
    const int* __restrict__ deg, int n, int* __restrict__ partial) {
  __shared__ int sm[256];
  int base = blockIdx.x * 1024;
  int t = threadIdx.x;
  int sum = 0;
#pragma unroll
  for (int k = 0; k < 4; ++k) {
    int i = base + k * 256 + t;
    sum += (i < n) ? deg[i] : 0;
  }
  sm[t] = sum;
  __syncthreads();
  for (int off = 128; off > 0; off >>= 1) {
    if (t < off) sm[t] += sm[t + off];
    __syncthreads();
  }
  if (t == 0) partial[blockIdx.x] = sm[0];
}

__global__ void scan_partial_kernel(int* __restrict__ partial, int nchunks) {
  int lane = threadIdx.x;  // 64 threads
  int v = (lane < nchunks) ? partial[lane] : 0;
#pragma unroll
  for (int off = 1; off < 64; off <<= 1) {
    int u = __shfl_up(v, off, 64);
    if (lane >= off) v += u;
  }
  int ex = __shfl_up(v, 1, 64);
  if (lane == 0) ex = 0;
  if (lane < nchunks) partial[lane] = ex;
}

__global__ __launch_bounds__(1024) void block_scan_kernel(
    const int* __restrict__ deg, const int* __restrict__ partial,
    int* __restrict__ row_ptr, int* __restrict__ cursor, int n) {
  __shared__ int sm[1024];
  int i = blockIdx.x * 1024 + threadIdx.x;
  int v = (i < n) ? deg[i] : 0;
  sm[threadIdx.x] = v;
  __syncthreads();
  for (int off = 1; off < 1024; off <<= 1) {
    int t = (threadIdx.x >= off) ? sm[threadIdx.x - off] : 0;
    __syncthreads();
    sm[threadIdx.x] += t;
    __syncthreads();
  }
  int excl = partial[blockIdx.x] + sm[threadIdx.x] - v;
  if (i < n) {
    row_ptr[i] = excl;
    cursor[i] = excl;
  }
  if (i == n - 1) row_ptr[n] = excl + v;
}

__global__ void scatter_kernel(const int* __restrict__ src,
                               const int* __restrict__ dst, int E, int n,
                               int* __restrict__ cursor,
                               int* __restrict__ col_src) {
  int i = blockIdx.x * blockDim.x + threadIdx.x;
  int tot = E + n;
  if (i < tot) {
    int s = (i < E) ? src[i] : (i - E);
    int d = (i < E) ? dst[i] : (i - E);
    int slot = atomicAdd(&cursor[d], 1);
    col_src[slot] = s;
  }
}

// --------------------------- weight packing --------------------------------
// Fragment order for mfma_f32_16x16x32_bf16 B operand:
//   idx = ((ks*ntiles + t)*64 + lane)*8 + i -> W[ks*32+8*(lane>>4)+i][16t+(lane&15)]
// Zero-pads columns c >= N (classifier: 40 cols padded to 3 tiles = 48).
struct PackArgs {
  const float* w[7];
  ushort_t* hi[7];
  ushort_t* lo[7];
  int ntiles[7];
  int kslices[7];
  int N[7];
};

__global__ __launch_bounds__(256) void pack_w_kernel(PackArgs a) {
  int m = blockIdx.y;
  int ntiles = a.ntiles[m];
  int N = a.N[m];
  int tot = a.kslices[m] * ntiles * 512;
  int idx = blockIdx.x * 256 + threadIdx.x;
  if (idx >= tot) return;
  int i = idx & 7;
  int lane = (idx >> 3) & 63;
  int t = (idx >> 9) % ntiles;
  int ks = idx / (512 * ntiles);
  int k = ks * 32 + (lane >> 4) * 8 + i;
  int c = t * 16 + (lane & 15);
  float f = (c < N) ? a.w[m][k * N + c] : 0.f;
  ushort_t h = bf16_rne(f);
  a.hi[m][idx] = h;
  a.lo[m][idx] = bf16_rne(f - bf16_to_f(h));
}

// ----------------------- fused dual MFMA GEMM ------------------------------
// Yl (fp16) = X@Wl+Bl, Yr (fp16) = X@Wr+Br.  X: [M][128] fp32 OR fp16.
// Block: 256 thr = 4 waves; wave handles 16 rows x 128 cols (8 16x16 tiles).
// grid.y selects a 128-col panel (for N=256).
template <typename TIN>
__global__ __launch_bounds__(256) void gemm_dual_mfma(
    const TIN* __restrict__ X, const ushort_t* __restrict__ wlhi,
    const ushort_t* __restrict__ wllo, const ushort_t* __restrict__ wrhi,
    const ushort_t* __restrict__ wrlo, const float* __restrict__ Bl,
    const float* __restrict__ Br, _Float16* __restrict__ Yl,
    _Float16* __restrict__ Yr, int M, int N, int ntot) {
  int lane = threadIdx.x & 63;
  int wv = threadIdx.x >> 6;
  int kg = lane >> 4;  // 0..3
  int li = lane & 15;
  int rbase = blockIdx.x * 64 + wv * 16;
  int colofs = blockIdx.y * 128;
  int tbase = colofs >> 4;
  int arow = rbase + li;
  int ar = (arow < M) ? arow : (M - 1);
  const TIN* xp = X + (size_t)ar * 128 + kg * 8;

  f32x4 accl[8], accr[8];
#pragma unroll
  for (int t = 0; t < 8; ++t) {
    accl[t] = (f32x4){0.f, 0.f, 0.f, 0.f};
    accr[t] = (f32x4){0.f, 0.f, 0.f, 0.f};
  }

#pragma unroll
  for (int ks = 0; ks < 4; ++ks) {
    float av[8];
    if constexpr (sizeof(TIN) == 4) {
      float4 a0 = *reinterpret_cast<const float4*>(xp + ks * 32);
      float4 a1 = *reinterpret_cast<const float4*>(xp + ks * 32 + 4);
      av[0] = a0.x; av[1] = a0.y; av[2] = a0.z; av[3] = a0.w;
      av[4] = a1.x; av[5] = a1.y; av[6] = a1.z; av[7] = a1.w;
    } else {
      half8 h8 = *reinterpret_cast<const half8*>(xp + ks * 32);
#pragma unroll
      for (int i = 0; i < 8; ++i) av[i] = (float)h8[i];
    }
    bf16x8 ah, al;
#pragma unroll
    for (int i = 0; i < 8; ++i) {
      ushort_t h = bf16_rne(av[i]);
      ah[i] = (short)h;
      al[i] = (short)bf16_rne(av[i] - bf16_to_f(h));
    }
    size_t fb = ((size_t)ks * ntot + tbase) * 512 + (size_t)lane * 8;
#pragma unroll
    for (int t = 0; t < 8; ++t) {
      size_t o = fb + (size_t)t * 512;
      bf16x8 blh = *reinterpret_cast<const bf16x8*>(wlhi + o);
      bf16x8 bll = *reinterpret_cast<const bf16x8*>(wllo + o);
      bf16x8 brh = *reinterpret_cast<const bf16x8*>(wrhi + o);
      bf16x8 brl = *reinterpret_cast<const bf16x8*>(wrlo + o);
      accl[t] = __builtin_amdgcn_mfma_f32_16x16x32_bf16(ah, blh, accl[t], 0, 0, 0);
      accl[t] = __builtin_amdgcn_mfma_f32_16x16x32_bf16(ah, bll, accl[t], 0, 0, 0);
      accl[t] = __builtin_amdgcn_mfma_f32_16x16x32_bf16(al, blh, accl[t], 0, 0, 0);
      accr[t] = __builtin_amdgcn_mfma_f32_16x16x32_bf16(ah, brh, accr[t], 0, 0, 0);
      accr[t] = __builtin_amdgcn_mfma_f32_16x16x32_bf16(ah, brl, accr[t], 0, 0, 0);
      accr[t] = __builtin_amdgcn_mfma_f32_16x16x32_bf16(al, brh, accr[t], 0, 0, 0);
    }
  }
  // D layout: row = 4*(lane>>4)+reg, col = 16t + (lane&15)
  int srow = rbase + kg * 4;
#pragma unroll
  for (int t = 0; t < 8; ++t) {
    int col = colofs + t * 16 + li;
    float bl = Bl[col];
    float br = Br[col];
#pragma unroll
    for (int r = 0; r < 4; ++r) {
      int rr = srow + r;
      if (rr < M) {
        Yl[(size_t)rr * N + col] = (_Float16)(accl[t][r] + bl);
        Yr[(size_t)rr * N + col] = (_Float16)(accr[t][r] + br);
      }
    }
  }
}

// ----------------------- classifier via MFMA -------------------------------
// out[M][40] = H[M][256] @ WC[256][40] + BC.  H fp16. WC packed to 3 tiles.
__global__ __launch_bounds__(256) void classifier_mfma(
    const _Float16* __restrict__ H, const ushort_t* __restrict__ wchi,
    const ushort_t* __restrict__ wclo, const float* __restrict__ BC,
    float* __restrict__ out, int M) {
  int lane = threadIdx.x & 63;
  int wv = threadIdx.x >> 6;
  int kg = lane >> 4;
  int li = lane & 15;
  int rbase = blockIdx.x * 64 + wv * 16;
  int arow = rbase + li;
  int ar = (arow < M) ? arow : (M - 1);
  const _Float16* xp = H + (size_t)ar * 256 + kg * 8;

  f32x4 acc[3];
#pragma unroll
  for (int t = 0; t < 3; ++t) acc[t] = (f32x4){0.f, 0.f, 0.f, 0.f};

#pragma unroll
  for (int ks = 0; ks < 8; ++ks) {
    half8 h8 = *reinterpret_cast<const half8*>(xp + ks * 32);
    bf16x8 ah, al;
#pragma unroll
    for (int i = 0; i < 8; ++i) {
      float f = (float)h8[i];
      ushort_t h = bf16_rne(f);
      ah[i] = (short)h;
      al[i] = (short)bf16_rne(f - bf16_to_f(h));
    }
    size_t fb = ((size_t)ks * 3) * 512 + (size_t)lane * 8;
#pragma unroll
    for (int t = 0; t < 3; ++t) {
      size_t o = fb + (size_t)t * 512;
      bf16x8 bh = *reinterpret_cast<const bf16x8*>(wchi + o);
      bf16x8 bl = *reinterpret_cast<const bf16x8*>(wclo + o);
      acc[t] = __builtin_amdgcn_mfma_f32_16x16x32_bf16(ah, bh, acc[t], 0, 0, 0);
      acc[t] = __builtin_amdgcn_mfma_f32_16x16x32_bf16(ah, bl, acc[t], 0, 0, 0);
      acc[t] = __builtin_amdgcn_mfma_f32_16x16x32_bf16(al, bh, acc[t], 0, 0, 0);
    }
  }
  int srow = rbase + kg * 4;
#pragma unroll
  for (int t = 0; t < 3; ++t) {
    int col = t * 16 + li;
    if (col < 40) {
      float b = BC[col];
#pragma unroll
      for (int r = 0; r < 4; ++r) {
        int rr = srow + r;
        if (rr < M) out[(size_t)rr * 40 + col] = acc[t][r] + b;
      }
    }
  }
}

// --------------------------- attention -------------------------------------
// r8's 3-stage shift pipeline (measured best): xv/xn/x2 half8 buffers,
// gather for edge j+8 issued at TOP of the body with index i2 staged one
// iteration earlier; score on xv; shift. Packed fp16 score, defer-max
// (THR=8), mixed-precision aggregation (v_fma_mix: fp16 operand, fp32
// accumulate — no fp32 staging array), fp16 output.
// Per-lane columns (half8): chunk q8 covers cols q8*128 + sl*8 + [0,8).
#define NEG_BIG (-1e30f)
template <int DOUT, bool RELU>
__global__ __launch_bounds__(256) void attn_kernel(
    const _Float16* __restrict__ xl, const _Float16* __restrict__ xr,
    const float* __restrict__ att, const float* __restrict__ bias,
    const int* __restrict__ row_ptr, const int* __restrict__ col_src,
    _Float16* __restrict__ out, int M) {
  constexpr int NQ8 = DOUT / 128;  // half8 (16B) gathers per lane per edge
  constexpr int NE = DOUT / 16;    // fp32 acc elements per lane
  constexpr int NP = NE / 2;       // half2 pairs per lane
  int wid = (int)((blockIdx.x * blockDim.x + threadIdx.x) >> 6);
  int lane = threadIdx.x & 63;
  int grp = lane >> 4;
  int sl = lane & 15;
  if (wid >= M) return;

  half2v xr2[NP], att2[NP];
  {
    const half8* xrp =
        reinterpret_cast<const half8*>(xr) + (size_t)wid * (DOUT / 8) + sl;
#pragma unroll
    for (int q = 0; q < NQ8; ++q) {
      half8 r8 = xrp[q * 16];
#pragma unroll
      for (int t = 0; t < 4; ++t) {
        half2v v;
        v[0] = r8[2 * t];
        v[1] = r8[2 * t + 1];
        xr2[q * 4 + t] = v;
      }
    }
#pragma unroll
    for (int q = 0; q < NQ8; ++q) {
#pragma unroll
      for (int t = 0; t < 4; ++t) {
        int c = q * 128 + sl * 8 + t * 2;
        half2v a2;
        a2[0] = (_Float16)att[c];
        a2[1] = (_Float16)att[c + 1];
        att2[q * 4 + t] = a2;
      }
    }
  }
  half2v v02;
  v02[0] = (_Float16)0.2f;
  v02[1] = (_Float16)0.2f;

  float acc[NE];
#pragma unroll
  for (int i = 0; i < NE; ++i) acc[i] = 0.f;
  float m = NEG_BIG, s = 0.f;
  int e0 = row_ptr[wid], e1 = row_ptr[wid + 1];
  int j = e0 + grp;  // this group's edge stream: j, j+4, j+8, ...

  const half8* base = reinterpret_cast<const half8*>(xl);
  half8 xv[NQ8], xn[NQ8], x2[NQ8];
  half8 hz;
#pragma unroll
  for (int i = 0; i < 8; ++i) hz[i] = (_Float16)0.f;
#pragma unroll
  for (int q = 0; q < NQ8; ++q) {
    xv[q] = hz;
    xn[q] = hz;
    x2[q] = hz;
  }
  if (j < e1) {
    const half8* rp = base + (size_t)col_src[j] * (DOUT / 8) + sl;
#pragma unroll
    for (int q = 0; q < NQ8; ++q) xv[q] = rp[q * 16];
  }
  if (j + 4 < e1) {
    const half8* rp = base + (size_t)col_src[j + 4] * (DOUT / 8) + sl;
#pragma unroll
    for (int q = 0; q < NQ8; ++q) xn[q] = rp[q * 16];
  }
  int i2 = (j + 8 < e1) ? col_src[j + 8] : 0;

  while (j < e1) {
    int i3 = (j + 12 < e1) ? col_src[j + 12] : 0;  // index prefetch
    if (j + 8 < e1) {  // issue gather for edge j+8 (2 in flight)
      const half8* rp = base + (size_t)i2 * (DOUT / 8) + sl;
#pragma unroll
      for (int q = 0; q < NQ8; ++q) x2[q] = rp[q * 16];
    }
    // packed fp16 score
    float p = 0.f;
#pragma unroll
    for (int q = 0; q < NQ8; ++q) {
#pragma unroll
      for (int t = 0; t < 4; ++t) {
        half2v xa;
        xa[0] = xv[q][2 * t];
        xa[1] = xv[q][2 * t + 1];
        half2v tt = xa + xr2[q * 4 + t];
        tt = h2max(tt, tt * v02);  // leaky_relu 0.2
        p = fdot2f(tt, att2[q * 4 + t], p);
      }
    }
#pragma unroll
    for (int off = 1; off < 16; off <<= 1) p += __shfl_xor(p, off, 64);
    // mixed-precision aggregation straight from the fp16 buffer
    // (fmaf(pe, (float)h16, acc) -> v_fma_mix_f32, no cvt pass)
    if (p > m + 8.0f) {  // rare: move reference max
      float sc = __expf(m - p);
      s = s * sc + 1.f;
#pragma unroll
      for (int q = 0; q < NQ8; ++q)
#pragma unroll
        for (int u = 0; u < 8; ++u)
          acc[q * 8 + u] = fmaf(acc[q * 8 + u], sc, (float)xv[q][u]);
      m = p;
    } else {  // common: no rescale, p - m <= 8 so pe <= e^8
      float pe = __expf(p - m);
      s += pe;
#pragma unroll
      for (int q = 0; q < NQ8; ++q)
#pragma unroll
        for (int u = 0; u < 8; ++u)
          acc[q * 8 + u] = fmaf(pe, (float)xv[q][u], acc[q * 8 + u]);
    }
#pragma unroll
    for (int q = 0; q < NQ8; ++q) {
      xv[q] = xn[q];
      xn[q] = x2[q];
    }
    i2 = i3;
    j += 4;
  }
  // merge (m, s) across the 4 groups (m is each group's reference point)
  float mg = m;
  float mm = m, ss = s;
#pragma unroll
  for (int off = 16; off < 64; off <<= 1) {
    float mo = __shfl_xor(mm, off, 64);
    float so = __shfl_xor(ss, off, 64);
    float nm = fmaxf(mm, mo);
    ss = ss * __expf(mm - nm) + so * __expf(mo - nm);
    mm = nm;
  }
  float scale = __expf(mg - mm) / ss;  // ss > 0 (deg >= 1 via self-loop)
#pragma unroll
  for (int i = 0; i < NE; ++i) {
    float v = acc[i] * scale;
#pragma unroll
    for (int off = 16; off < 64; off <<= 1) v += __shfl_xor(v, off, 64);
    acc[i] = v;
  }
  // write: lane sl owns cols q8*128 + sl*8 + [0,8); group g writes
  // (q8 = g>>1, half hf = g&1) for DOUT=256; groups 0,1 write for DOUT=128.
  if (NQ8 == 1) {
    if (grp < 2) {
      int c = sl * 8 + grp * 4;
      float4 b4 = *reinterpret_cast<const float4*>(bias + c);
      float o0 = acc[grp * 4 + 0] + b4.x;
      float o1 = acc[grp * 4 + 1] + b4.y;
      float o2 = acc[grp * 4 + 2] + b4.z;
      float o3 = acc[grp * 4 + 3] + b4.w;
      if (RELU) {
        o0 = fmaxf(o0, 0.f); o1 = fmaxf(o1, 0.f);
        o2 = fmaxf(o2, 0.f); o3 = fmaxf(o3, 0.f);
      }
      half4 oh;
      oh[0] = (_Float16)o0; oh[1] = (_Float16)o1;
      oh[2] = (_Float16)o2; oh[3] = (_Float16)o3;
      *reinterpret_cast<half4*>(out + (size_t)wid * DOUT + c) = oh;
    }
  } else {
    int q8 = grp >> 1, hf = grp & 1;
    int c = q8 * 128 + sl * 8 + hf * 4;
    float4 b4 = *reinterpret_cast<const float4*>(bias + c);
    float o0 = acc[q8 * 8 + hf * 4 + 0] + b4.x;
    float o1 = acc[q8 * 8 + hf * 4 + 1] + b4.y;
    float o2 = acc[q8 * 8 + hf * 4 + 2] + b4.z;
    float o3 = acc[q8 * 8 + hf * 4 + 3] + b4.w;
    if (RELU) {
      o0 = fmaxf(o0, 0.f); o1 = fmaxf(o1, 0.f);
      o2 = fmaxf(o2, 0.f); o3 = fmaxf(o3, 0.f);
    }
    half4 oh;
    oh[0] = (_Float16)o0; oh[1] = (_Float16)o1;
    oh[2] = (_Float16)o2; oh[3] = (_Float16)o3;
    *reinterpret_cast<half4*>(out + (size_t)wid * DOUT + c) = oh;
  }
}

extern "C" void kernel_launch(void* const* d_in, const int* in_sizes, int n_in,
                              void* d_out, int out_size, void* d_ws,
                              size_t ws_size, hipStream_t stream) {
  const float* x = (const float*)d_in[0];
  const int* ei = (const int*)d_in[1];
  const float* w1l = (const float*)d_in[2];
  const float* b1l = (const float*)d_in[3];
  const float* w1r = (const float*)d_in[4];
  const float* b1r = (const float*)d_in[5];
  const float* a1 = (const float*)d_in[6];
  const float* o1 = (const float*)d_in[7];
  const float* w2l = (const float*)d_in[8];
  const float* b2l = (const float*)d_in[9];
  const float* w2r = (const float*)d_in[10];
  const float* b2r = (const float*)d_in[11];
  const float* a2 = (const float*)d_in[12];
  const float* o2 = (const float*)d_in[13];
  const float* w3l = (const float*)d_in[14];
  const float* b3l = (const float*)d_in[15];
  const float* w3r = (const float*)d_in[16];
  const float* b3r = (const float*)d_in[17];
  const float* a3 = (const float*)d_in[18];
  const float* o3 = (const float*)d_in[19];
  const float* wc = (const float*)d_in[20];
  const float* bc = (const float*)d_in[21];
  float* out = (float*)d_out;

  const int n = in_sizes[0] / 128;  // 50000
  const int E = in_sizes[1] / 2;    // 800000
  const int tot = E + n;
  const int nchunks = (n + 1023) / 1024;  // <= 64 required

  // workspace layout
  char* p = (char*)d_ws;
  int* row_ptr = (int*)p; p += (size_t)(n + 1) * 4;
  int* deg = (int*)p;     p += (size_t)n * 4;
  int* cursor = (int*)p;  p += (size_t)n * 4;
  int* partial = (int*)p; p += (size_t)64 * 4;
  int* col_src = (int*)p; p += (size_t)tot * 4;
  p = (char*)(((uintptr_t)p + 255) & ~(uintptr_t)255);
  // packed weights: layers 1,2: 16384 elems; layer 3: 32768; wc: 12288
  const size_t SZ12 = 16384, SZ3 = 32768, SZC = 12288;
  ushort_t* pk[14];
  for (int i = 0; i < 8; ++i) { pk[i] = (ushort_t*)p; p += SZ12 * 2; }
  for (int i = 8; i < 12; ++i) { pk[i] = (ushort_t*)p; p += SZ3 * 2; }
  for (int i = 12; i < 14; ++i) { pk[i] = (ushort_t*)p; p += SZC * 2; }
  p = (char*)(((uintptr_t)p + 255) & ~(uintptr_t)255);
  _Float16* bufA = (_Float16*)p; p += (size_t)n * 256 * 2;  // h (fp16)
  _Float16* bufL = (_Float16*)p; p += (size_t)n * 256 * 2;  // xl (fp16)
  _Float16* bufR = (_Float16*)p;                            // xr (fp16)

  const int TPB = 256;

  // CSR build
  zero_int_kernel<<<(n + TPB - 1) / TPB, TPB, 0, stream>>>(deg, n);
  deg_count_kernel<<<(tot + TPB - 1) / TPB, TPB, 0, stream>>>(ei + E, E, n, deg);
  block_sum_kernel<<<nchunks, 256, 0, stream>>>(deg, n, partial);
  scan_partial_kernel<<<1, 64, 0, stream>>>(partial, nchunks);
  block_scan_kernel<<<nchunks, 1024, 0, stream>>>(deg, partial, row_ptr, cursor, n);
  scatter_kernel<<<(tot + TPB - 1) / TPB, TPB, 0, stream>>>(ei, ei + E, E, n,
                                                            cursor, col_src);

  // pack 6 weight matrices + classifier into MFMA B-fragment hi/lo arrays
  PackArgs pa;
  pa.w[0] = w1l; pa.w[1] = w1r; pa.w[2] = w2l; pa.w[3] = w2r;
  pa.w[4] = w3l; pa.w[5] = w3r; pa.w[6] = wc;
  pa.hi[0] = pk[0]; pa.lo[0] = pk[1];
  pa.hi[1] = pk[2]; pa.lo[1] = pk[3];
  pa.hi[2] = pk[4]; pa.lo[2] = pk[5];
  pa.hi[3] = pk[6]; pa.lo[3] = pk[7];
  pa.hi[4] = pk[8]; pa.lo[4] = pk[9];
  pa.hi[5] = pk[10]; pa.lo[5] = pk[11];
  pa.hi[6] = pk[12]; pa.lo[6] = pk[13];
  pa.ntiles[0] = pa.ntiles[1] = pa.ntiles[2] = pa.ntiles[3] = 8;
  pa.ntiles[4] = pa.ntiles[5] = 16;
  pa.ntiles[6] = 3;
  pa.kslices[0] = pa.kslices[1] = pa.kslices[2] = pa.kslices[3] = 4;
  pa.kslices[4] = pa.kslices[5] = 4;
  pa.kslices[6] = 8;
  pa.N[0] = pa.N[1] = pa.N[2] = pa.N[3] = 128;
  pa.N[4] = pa.N[5] = 256;
  pa.N[6] = 40;
  pack_w_kernel<<<dim3(128, 7), 256, 0, stream>>>(pa);

  const int gemmGrid = (n + 63) / 64;
  const int waveGrid = (n + 3) / 4;

  // Layer 1 (128 -> 128) + ReLU   (fp32 input x)
  gemm_dual_mfma<float><<<dim3(gemmGrid, 1), TPB, 0, stream>>>(
      x, pk[0], pk[1], pk[2], pk[3], b1l, b1r, bufL, bufR, n, 128, 8);
  attn_kernel<128, true><<<waveGrid, TPB, 0, stream>>>(bufL, bufR, a1, o1,
                                                       row_ptr, col_src, bufA, n);
  // Layer 2 (128 -> 128) + ReLU   (fp16 input h)
  gemm_dual_mfma<_Float16><<<dim3(gemmGrid, 1), TPB, 0, stream>>>(
      bufA, pk[4], pk[5], pk[6], pk[7], b2l, b2r, bufL, bufR, n, 128, 8);
  attn_kernel<128, true><<<waveGrid, TPB, 0, stream>>>(bufL, bufR, a2, o2,
                                                       row_ptr, col_src, bufA, n);
  // Layer 3 (128 -> 256), no ReLU (fp16 input h)
  gemm_dual_mfma<_Float16><<<dim3(gemmGrid, 2), TPB, 0, stream>>>(
      bufA, pk[8], pk[9], pk[10], pk[11], b3l, b3r, bufL, bufR, n, 256, 16);
  attn_kernel<256, false><<<waveGrid, TPB, 0, stream>>>(bufL, bufR, a3, o3,
                                                        row_ptr, col_src, bufA, n);
  // Classifier (256 -> 40) via MFMA (fp16 input h)
  classifier_mfma<<<gemmGrid, TPB, 0, stream>>>(bufA, pk[12], pk[13], bc, out, n);
}